// Round 8
// baseline (283.263 us; speedup 1.0000x reference)
//
#include <hip/hip_runtime.h>
#include <hip/hip_fp16.h>
#include <math.h>

// ---------------------------------------------------------------------------
// GAT 2-layer forward, N=50000, E=800000 (+N self loops), EMB=128,
// layer1: heads=8, C=16 (concat -> 128), layer2: heads=1, C=64.
// CSR-by-dst build per call, fused GEMM+alpha epilogues, one gather pass per
// layer, softmax without max-subtraction. h1/h2/act1 in fp16.
// R8: gemms rewritten with 8x8 / 8x4 register tiles (128-row block tiles,
//     padded Xs[r][33] so per-row broadcasts are conflict-free) -> VALU-bound
//     instead of LDS-issue-bound; hist blocks FIRST in the fat kernel.
// ---------------------------------------------------------------------------

__global__ __launch_bounds__(256) void scan1_kernel(const int* __restrict__ deg, int N,
                                                    int* __restrict__ rowstart,
                                                    int* __restrict__ blocksum) {
    __shared__ int tmp[256];
    int t = threadIdx.x;
    int i = blockIdx.x * 256 + t;
    int v = (i < N) ? deg[i] : 0;
    tmp[t] = v;
    __syncthreads();
    for (int off = 1; off < 256; off <<= 1) {
        int x = (t >= off) ? tmp[t - off] : 0;
        __syncthreads();
        tmp[t] += x;
        __syncthreads();
    }
    if (i < N) rowstart[i] = tmp[t] - v;
    if (t == 255) blocksum[blockIdx.x] = tmp[t];
}

// Fused scan2+scan3: block b computes offset = sum(blocksum[0..b-1]) via a
// masked LDS reduce (nb<=256), then adds it to its rowstart slice and
// initializes cursor.
__global__ __launch_bounds__(256) void scan23_kernel(int* __restrict__ rowstart,
                                                     const int* __restrict__ blocksum,
                                                     int nb,
                                                     int* __restrict__ cursor,
                                                     int N, int E) {
    __shared__ int sdata[256];
    int t = threadIdx.x;
    int b = blockIdx.x;
    sdata[t] = (t < nb && t < b) ? blocksum[t] : 0;
    __syncthreads();
#pragma unroll
    for (int off = 128; off > 0; off >>= 1) {
        if (t < off) sdata[t] += sdata[t + off];
        __syncthreads();
    }
    int offset = sdata[0];
    int i = b * 256 + t;
    if (i < N) {
        int v = rowstart[i] + offset;
        rowstart[i] = v;
        cursor[i] = v;
    } else if (i == N) {
        rowstart[N] = E;
    }
}

// Bucketed scatter: block (blockIdx&7) commits only dst in its 1/8 range of
// nodes -> esrc write lines stay within one XCD's L2 (round-robin dispatch).
__global__ __launch_bounds__(256) void scatter_kernel(const int* __restrict__ src,
                                                      const int* __restrict__ dst,
                                                      int E, int N,
                                                      int* __restrict__ cursor,
                                                      int* __restrict__ esrc) {
    int b = blockIdx.x & 7;
    int chunk = blockIdx.x >> 3;
    int bdiv = (N + 7) >> 3;
    int blo = b * bdiv;
    int bhi = blo + bdiv;
    int base = chunk * 1024 + threadIdx.x;
#pragma unroll
    for (int u = 0; u < 4; u++) {
        int i = base + u * 256;
        if (i < E) {
            int d = dst[i];
            int s = src[i];
            if (d >= blo && d < bhi) {
                int p = atomicAdd(&cursor[d], 1);
                esrc[p] = s;
            }
        }
    }
}

// Fat kernel: blocks [0,GH) run the edge histogram (scheduled FIRST so they
// drain while gemm blocks run); blocks [GH, GH+G1) run GEMM1:
// h1[N,128] = x @ W1 (fp16 out) + per-head alpha dots.
// GEMM1 tile: 128 rows x 128 cols per block; thread owns 8 rows x 8 cols.
// Xs[r][33] padding: the 8 per-row b32 broadcasts come from 4 rg-groups whose
// addresses differ by 8*33 floats -> distinct banks, conflict-free.
__global__ __launch_bounds__(256) void gemm1_hist_kernel(const float* __restrict__ x,
                                                         const float* __restrict__ W,
                                                         const float* __restrict__ a_s,
                                                         const float* __restrict__ a_d,
                                                         __half* __restrict__ h1,
                                                         float* __restrict__ als,
                                                         float* __restrict__ ald, int N,
                                                         const int* __restrict__ dst,
                                                         int E, int* __restrict__ deg,
                                                         int GH) {
    if ((int)blockIdx.x < GH) {  // ---- histogram part (first) ----
        int i = (blockIdx.x * 256 + threadIdx.x) * 4;
        if (i + 3 < E) {
            int4 d = *(const int4*)(dst + i);
            atomicAdd(&deg[d.x], 1);
            atomicAdd(&deg[d.y], 1);
            atomicAdd(&deg[d.z], 1);
            atomicAdd(&deg[d.w], 1);
        } else {
            for (int k = i; k < E; k++) atomicAdd(&deg[dst[k]], 1);
        }
        return;
    }
    // ---- GEMM1 part ----
    __shared__ float Xs[128 * 33];  // 16.9 KB (row stride 33)
    __shared__ float Ws[32 * 128];  // 16 KB (K-slice of W1)
    int t = threadIdx.x;
    int row0 = (blockIdx.x - GH) * 128;
    int cg = t & 15;   // cols cg*8 .. cg*8+7
    int rg = t >> 4;   // rows rg*8 .. rg*8+7
    float acc[8][8];
#pragma unroll
    for (int i = 0; i < 8; i++)
#pragma unroll
        for (int j = 0; j < 8; j++) acc[i][j] = 0.f;

    for (int kt = 0; kt < 4; kt++) {
        __syncthreads();
        {   // stage W K-slice: rows kt*32..+31, all 128 cols (contiguous)
            const float4* wv = (const float4*)(W + (size_t)kt * 32 * 128);
            float4* Wv = (float4*)Ws;
            for (int i = t; i < 1024; i += 256) Wv[i] = wv[i];
        }
        {   // stage X slice: 128 rows x 32 k (padded rows)
            for (int i = t; i < 1024; i += 256) {
                int r = i >> 3, c8 = i & 7;
                int gr = row0 + r;
                float4 v = make_float4(0.f, 0.f, 0.f, 0.f);
                if (gr < N) v = *(const float4*)(x + (size_t)gr * 128 + kt * 32 + c8 * 4);
                float* dp = Xs + r * 33 + c8 * 4;
                dp[0] = v.x; dp[1] = v.y; dp[2] = v.z; dp[3] = v.w;
            }
        }
        __syncthreads();
        const float* xb = Xs + rg * 8 * 33;
#pragma unroll 2
        for (int k = 0; k < 32; k++) {
            const float4* wr = (const float4*)(Ws + k * 128 + cg * 8);
            float4 w0 = wr[0], w1 = wr[1];
#pragma unroll
            for (int i = 0; i < 8; i++) {
                float xi = xb[i * 33 + k];
                acc[i][0] += xi * w0.x; acc[i][1] += xi * w0.y;
                acc[i][2] += xi * w0.z; acc[i][3] += xi * w0.w;
                acc[i][4] += xi * w1.x; acc[i][5] += xi * w1.y;
                acc[i][6] += xi * w1.z; acc[i][7] += xi * w1.w;
            }
        }
    }
    // epilogue: fp16 store + per-head alpha dots (8 cols = half a head; pair
    // lanes cg, cg^1 share head cg>>1 -> one shfl_xor combine)
    int head = cg >> 1;
    int abase = head * 16 + (cg & 1) * 8;
    float asv[8], adv[8];
#pragma unroll
    for (int j = 0; j < 8; j++) {
        asv[j] = a_s[abase + j];
        adv[j] = a_d[abase + j];
    }
#pragma unroll
    for (int i = 0; i < 8; i++) {
        int n = row0 + rg * 8 + i;
        if (n < N) {
            __align__(16) __half2 pk[4];
#pragma unroll
            for (int j = 0; j < 4; j++)
                pk[j] = __floats2half2_rn(acc[i][2 * j], acc[i][2 * j + 1]);
            *(float4*)(h1 + (size_t)n * 128 + cg * 8) = *(float4*)pk;
            float ds = 0.f, dd = 0.f;
#pragma unroll
            for (int j = 0; j < 8; j++) {
                ds += acc[i][j] * asv[j];
                dd += acc[i][j] * adv[j];
            }
            ds += __shfl_xor(ds, 1, 64);
            dd += __shfl_xor(dd, 1, 64);
            if ((cg & 1) == 0) {
                als[n * 8 + head] = ds;
                ald[n * 8 + head] = dd;
            }
        }
    }
}

// Aggregation layer 1, node-per-group: wave = 8 nodes x 8 lanes. Lane q of
// group g owns head q's 16 channels of node (base+g); walks that node's edge
// list privately -> per-head softmax per-lane, no cross-lane reduction.
__global__ __launch_bounds__(256) void agg1_kernel(const __half* __restrict__ h1,
                                                   const float* __restrict__ als,
                                                   const float* __restrict__ ald,
                                                   const int* __restrict__ rowstart,
                                                   const int* __restrict__ esrc,
                                                   const float* __restrict__ b1,
                                                   __half* __restrict__ act1, int N) {
    int t = threadIdx.x;
    int lane = t & 63;
    int grp = lane >> 3;
    int q = lane & 7;  // head q, channels 16q..16q+15
    int n = blockIdx.x * 32 + (t >> 6) * 8 + grp;
    if (n >= N) return;
    const float4* h1v = (const float4*)h1;  // 16 float4 per row
    float adv = ald[n * 8 + q];
    float acc[16];
    float wsum;
    {  // self loop
        float e = als[n * 8 + q] + adv;
        e = (e > 0.f) ? e : 0.2f * e;
        float w = __expf(e);
        wsum = w;
        float4 hv0 = h1v[(size_t)n * 16 + 2 * q];
        float4 hv1 = h1v[(size_t)n * 16 + 2 * q + 1];
        const __half2* p0 = (const __half2*)&hv0;
        const __half2* p1 = (const __half2*)&hv1;
#pragma unroll
        for (int k = 0; k < 4; k++) {
            float2 f = __half22float2(p0[k]);
            acc[2 * k] = w * f.x;
            acc[2 * k + 1] = w * f.y;
        }
#pragma unroll
        for (int k = 0; k < 4; k++) {
            float2 f = __half22float2(p1[k]);
            acc[8 + 2 * k] = w * f.x;
            acc[8 + 2 * k + 1] = w * f.y;
        }
    }
    int beg = rowstart[n], end = rowstart[n + 1];
    for (int j = beg; j < end; j++) {
        int s = esrc[j];
        float e = als[s * 8 + q] + adv;
        e = (e > 0.f) ? e : 0.2f * e;
        float w = __expf(e);
        wsum += w;
        float4 hv0 = h1v[(size_t)s * 16 + 2 * q];
        float4 hv1 = h1v[(size_t)s * 16 + 2 * q + 1];
        const __half2* p0 = (const __half2*)&hv0;
        const __half2* p1 = (const __half2*)&hv1;
#pragma unroll
        for (int k = 0; k < 4; k++) {
            float2 f = __half22float2(p0[k]);
            acc[2 * k] += w * f.x;
            acc[2 * k + 1] += w * f.y;
        }
#pragma unroll
        for (int k = 0; k < 4; k++) {
            float2 f = __half22float2(p1[k]);
            acc[8 + 2 * k] += w * f.x;
            acc[8 + 2 * k + 1] += w * f.y;
        }
    }
    float inv = 1.f / (wsum + 1e-16f);
    const float* bf = b1 + q * 16;
    __align__(16) __half2 po[8];
#pragma unroll
    for (int k = 0; k < 8; k++) {
        float o0 = acc[2 * k] * inv + bf[2 * k];
        float o1 = acc[2 * k + 1] * inv + bf[2 * k + 1];
        o0 = (o0 > 0.f) ? o0 : (__expf(o0) - 1.f);  // ELU
        o1 = (o1 > 0.f) ? o1 : (__expf(o1) - 1.f);
        po[k] = __floats2half2_rn(o0, o1);
    }
    float4* ov = (float4*)(act1 + (size_t)n * 128 + q * 16);
    ov[0] = ((float4*)po)[0];
    ov[1] = ((float4*)po)[1];
}

// GEMM2: h2[N,64] = act1[N,128](fp16) @ W2[128,64] (fp16 out).
// Tile: 128 rows x 64 cols per block; thread owns 8 rows x 4 cols; whole W2
// in LDS; act1 staged fp16->fp32 into padded Xs[r][33] per 32-K slice.
__global__ __launch_bounds__(256) void gemm2_kernel(const __half* __restrict__ act1,
                                                    const float* __restrict__ W2,
                                                    const float* __restrict__ a2s,
                                                    const float* __restrict__ a2d,
                                                    __half* __restrict__ h2,
                                                    float* __restrict__ al2s,
                                                    float* __restrict__ al2d, int N) {
    __shared__ float Ws[128 * 64];  // 32 KB
    __shared__ float Xs[128 * 33];  // 16.9 KB
    int t = threadIdx.x;
    int row0 = blockIdx.x * 128;
    int cg = t & 15;   // cols cg*4 .. cg*4+3
    int rg = t >> 4;   // rows rg*8 .. rg*8+7
    {
        const float4* wv = (const float4*)W2;
        float4* Wv = (float4*)Ws;
        for (int i = t; i < 2048; i += 256) Wv[i] = wv[i];
    }
    float acc[8][4];
#pragma unroll
    for (int i = 0; i < 8; i++)
#pragma unroll
        for (int j = 0; j < 4; j++) acc[i][j] = 0.f;

    for (int kt = 0; kt < 4; kt++) {
        __syncthreads();
        {   // stage act1 slice: 128 rows x 32 k, fp16 -> fp32
            for (int i = t; i < 1024; i += 256) {
                int r = i >> 3, c8 = i & 7;
                int gr = row0 + r;
                float2 raw = make_float2(0.f, 0.f);
                if (gr < N)
                    raw = *(const float2*)(act1 + (size_t)gr * 128 + kt * 32 + c8 * 4);
                const __half2* hp = (const __half2*)&raw;
                float2 f0 = __half22float2(hp[0]);
                float2 f1 = __half22float2(hp[1]);
                float* dp = Xs + r * 33 + c8 * 4;
                dp[0] = f0.x; dp[1] = f0.y; dp[2] = f1.x; dp[3] = f1.y;
            }
        }
        __syncthreads();
        const float* xb = Xs + rg * 8 * 33;
#pragma unroll 2
        for (int k = 0; k < 32; k++) {
            float4 w = *(const float4*)(Ws + (kt * 32 + k) * 64 + cg * 4);
#pragma unroll
            for (int i = 0; i < 8; i++) {
                float xi = xb[i * 33 + k];
                acc[i][0] += xi * w.x; acc[i][1] += xi * w.y;
                acc[i][2] += xi * w.z; acc[i][3] += xi * w.w;
            }
        }
    }
    float as0 = a2s[cg * 4], as1 = a2s[cg * 4 + 1], as2 = a2s[cg * 4 + 2], as3 = a2s[cg * 4 + 3];
    float ad0 = a2d[cg * 4], ad1 = a2d[cg * 4 + 1], ad2 = a2d[cg * 4 + 2], ad3 = a2d[cg * 4 + 3];
#pragma unroll
    for (int i = 0; i < 8; i++) {
        int n = row0 + rg * 8 + i;
        if (n < N) {
            __align__(8) __half2 pk[2];
            pk[0] = __floats2half2_rn(acc[i][0], acc[i][1]);
            pk[1] = __floats2half2_rn(acc[i][2], acc[i][3]);
            *(float2*)(h2 + (size_t)n * 64 + cg * 4) = *(float2*)pk;
            float ps = acc[i][0] * as0 + acc[i][1] * as1 + acc[i][2] * as2 + acc[i][3] * as3;
            float pd = acc[i][0] * ad0 + acc[i][1] * ad1 + acc[i][2] * ad2 + acc[i][3] * ad3;
#pragma unroll
            for (int off = 1; off < 16; off <<= 1) {
                ps += __shfl_xor(ps, off, 64);
                pd += __shfl_xor(pd, off, 64);
            }
            if (cg == 0) {
                al2s[n] = ps;
                al2d[n] = pd;
            }
        }
    }
}

// Aggregation layer 2, node-per-group: wave = 8 nodes x 8 lanes; lane q owns
// channels 8q..8q+7 of its group's node; walks the whole edge list privately.
__global__ __launch_bounds__(256) void agg2_kernel(const __half* __restrict__ h2,
                                                   const float* __restrict__ al2s,
                                                   const float* __restrict__ al2d,
                                                   const int* __restrict__ rowstart,
                                                   const int* __restrict__ esrc,
                                                   const float* __restrict__ b2,
                                                   float* __restrict__ out, int N) {
    int t = threadIdx.x;
    int lane = t & 63;
    int grp = lane >> 3;
    int q = lane & 7;  // channels 8q..8q+7
    int n = blockIdx.x * 32 + (t >> 6) * 8 + grp;
    if (n >= N) return;
    const float4* h2v = (const float4*)h2;  // 8 float4 per row
    float adv = al2d[n];
    float acc[8];
    float wsum;
    {  // self loop
        float e = al2s[n] + adv;
        e = (e > 0.f) ? e : 0.2f * e;
        float w = __expf(e);
        wsum = w;
        float4 hv = h2v[(size_t)n * 8 + q];
        const __half2* hp = (const __half2*)&hv;
#pragma unroll
        for (int k = 0; k < 4; k++) {
            float2 f = __half22float2(hp[k]);
            acc[2 * k] = w * f.x;
            acc[2 * k + 1] = w * f.y;
        }
    }
    int beg = rowstart[n], end = rowstart[n + 1];
    for (int j = beg; j < end; j++) {
        int s = esrc[j];
        float e = al2s[s] + adv;
        e = (e > 0.f) ? e : 0.2f * e;
        float w = __expf(e);
        wsum += w;
        float4 hv = h2v[(size_t)s * 8 + q];
        const __half2* hp = (const __half2*)&hv;
#pragma unroll
        for (int k = 0; k < 4; k++) {
            float2 f = __half22float2(hp[k]);
            acc[2 * k] += w * f.x;
            acc[2 * k + 1] += w * f.y;
        }
    }
    float inv = 1.f / (wsum + 1e-16f);
    const float* bf = b2 + q * 8;
    float4* ov = (float4*)(out + (size_t)n * 64 + q * 8);
    ov[0] = make_float4(acc[0] * inv + bf[0], acc[1] * inv + bf[1],
                        acc[2] * inv + bf[2], acc[3] * inv + bf[3]);
    ov[1] = make_float4(acc[4] * inv + bf[4], acc[5] * inv + bf[5],
                        acc[6] * inv + bf[6], acc[7] * inv + bf[7]);
}

extern "C" void kernel_launch(void* const* d_in, const int* in_sizes, int n_in,
                              void* d_out, int out_size, void* d_ws, size_t ws_size,
                              hipStream_t stream) {
    (void)n_in; (void)out_size; (void)ws_size;
    const float* x   = (const float*)d_in[0];
    const int*   ei  = (const int*)d_in[1];
    const float* W1  = (const float*)d_in[2];
    const float* a1s = (const float*)d_in[3];
    const float* a1d = (const float*)d_in[4];
    const float* b1  = (const float*)d_in[5];
    const float* W2  = (const float*)d_in[6];
    const float* a2s = (const float*)d_in[7];
    const float* a2d = (const float*)d_in[8];
    const float* b2  = (const float*)d_in[9];
    float* out = (float*)d_out;

    const int N = in_sizes[0] / 128;
    const int E = in_sizes[1] / 2;
    const int* src = ei;
    const int* dst = ei + E;

    char* wp = (char*)d_ws;
    auto alloc = [&](size_t bytes) -> void* {
        void* p = (void*)wp;
        wp += (bytes + 255) & ~(size_t)255;
        return p;
    };
    __half* h1   = (__half*)alloc((size_t)N * 128 * 2);
    __half* act1 = (__half*)alloc((size_t)N * 128 * 2);
    __half* h2   = (__half*)alloc((size_t)N * 64 * 2);
    float* al1s = (float*)alloc((size_t)N * 8 * 4);
    float* al1d = (float*)alloc((size_t)N * 8 * 4);
    float* al2s = (float*)alloc((size_t)N * 4);
    float* al2d = (float*)alloc((size_t)N * 4);
    int* deg      = (int*)alloc((size_t)N * 4);
    int* rowstart = (int*)alloc((size_t)(N + 1) * 4);
    int* cursor   = (int*)alloc((size_t)N * 4);
    int* esrc     = (int*)alloc((size_t)E * 4);
    int* blocksum = (int*)alloc(256 * 4);

    const int nbScan = (N + 255) / 256;
    const int gridH  = (E + 1023) / 1024;         // hist blocks (first)
    const int gridG1 = (N + 127) / 128;           // gemm1 blocks
    const int gridScat = ((E + 1023) / 1024) * 8;
    const int gridG2 = (N + 127) / 128;
    const int gridAggN = (N + 31) / 32;           // 8 nodes/wave, 4 waves/block

    hipMemsetAsync(deg, 0, (size_t)N * 4, stream);

    gemm1_hist_kernel<<<gridH + gridG1, 256, 0, stream>>>(
        x, W1, a1s, a1d, h1, al1s, al1d, N, dst, E, deg, gridH);
    scan1_kernel<<<nbScan, 256, 0, stream>>>(deg, N, rowstart, blocksum);
    scan23_kernel<<<(N + 256) / 256, 256, 0, stream>>>(rowstart, blocksum, nbScan,
                                                       cursor, N, E);
    scatter_kernel<<<gridScat, 256, 0, stream>>>(src, dst, E, N, cursor, esrc);

    agg1_kernel<<<gridAggN, 256, 0, stream>>>(h1, al1s, al1d, rowstart, esrc, b1, act1, N);
    gemm2_kernel<<<gridG2, 256, 0, stream>>>(act1, W2, a2s, a2d, h2, al2s, al2d, N);
    agg2_kernel<<<gridAggN, 256, 0, stream>>>(h2, al2s, al2d, rowstart, esrc, b2, out, N);
}